// Round 6
// baseline (5369.473 us; speedup 1.0000x reference)
//
#include <hip/hip_runtime.h>

// LSTM: T=512, B=64, I=512, H=512. ROUND 13b: intra-XCD coherence domain
// (round-13 compile-fixed: asm operands must be ext_vector_type, not the
// HIP uint4 struct -- clang can't pass struct inputs to asm).
//  Rounds 9-12 refuted: sync mechanism, x-proj latency, hop count, clock.
//  Invariant across all: agent-scope atomics -> every publish/poll crossed
//  the fabric to MALL (device coherence point; per-XCD L2s not coherent).
//  NOW: all communication confined to ONE XCD's shared L2 via sc0 (SE-scope,
//  old glc) ops: store sc0 lands in L2 (L1 write-through), load sc0 bypasses
//  L1 and reads same L2 -> ~200cy round trips instead of multi-us MALL hops.
//   - 2048 blocks launched; each reads HW_REG_XCC_ID; blocks on XCD 0 take
//     tickets; tickets 0..31 become the 32 workers (1/CU on the XCD's 32
//     CUs -- 136KB LDS forces 1 block/CU, so all 32 co-resident; workers
//     never exit, others return instantly).
//   - worker owns 16 h-cols; 4 gate n-tiles (one per gate) -> no shfl_xor,
//     no l15<8 divergence in the gate phase; all 64 lanes do gate math.
//   - h exchange: tag-in-data (r3 format), row-major [row][hcol] tagged u32;
//     consumer retry = ONE asm block of 32 global_load_dwordx4 sc0 with
//     immediate offsets + one vmcnt(0) = one pipelined L2 round trip.

#define T_STEPS 512
#define BATCH   64
#define HID     512
#define NW      32            // workers (= CUs per XCD)
#define GRID    2048
#define HBUF_BYTES (1 << 18)  // [2][64 rows][512 hcols] u32 tagged = 256 KB

typedef short bf16x8 __attribute__((ext_vector_type(8)));
typedef float f32x4  __attribute__((ext_vector_type(4)));
typedef unsigned int u32x4 __attribute__((ext_vector_type(4)));

__device__ __forceinline__ unsigned short f2bf(float f) {
    unsigned int u = __builtin_bit_cast(unsigned int, f);
    u += 0x7FFFu + ((u >> 16) & 1u);
    return (unsigned short)(u >> 16);
}
__device__ __forceinline__ unsigned int pack2(float lo, float hi) {
    return (unsigned int)f2bf(lo) | ((unsigned int)f2bf(hi) << 16);
}
__device__ __forceinline__ u32x4 cvt8(const float* __restrict__ p) {
    float4 f0 = *(const float4*)p;
    float4 f1 = *(const float4*)(p + 4);
    u32x4 r;
    r.x = pack2(f0.x, f0.y);
    r.y = pack2(f0.z, f0.w);
    r.z = pack2(f1.x, f1.y);
    r.w = pack2(f1.z, f1.w);
    return r;
}
__device__ __forceinline__ float sigmoidf_(float x) {
    return 1.0f / (1.0f + __expf(-x));
}
__device__ __forceinline__ float tanhf_(float x) {
    x = fminf(fmaxf(x, -15.f), 15.f);
    float e = __expf(2.0f * x);
    return (e - 1.0f) / (e + 1.0f);
}

// validate 4 tagged words (low16 must equal tgt)
#define VAL4(A) do { \
    m |= ((A.x ^ tgt) & 0xffffu); m |= ((A.y ^ tgt) & 0xffffu); \
    m |= ((A.z ^ tgt) & 0xffffu); m |= ((A.w ^ tgt) & 0xffffu); } while (0)

// repack 8 tagged words (A=j0..3, B=j4..7) -> bf16x8 A-fragment, 4 MFMAs
#define FRAGMFMA(KK, A, B) do { \
    u32x4 u_; \
    u_.x = (A.x >> 16) | (A.y & 0xffff0000u); \
    u_.y = (A.z >> 16) | (A.w & 0xffff0000u); \
    u_.z = (B.x >> 16) | (B.y & 0xffff0000u); \
    u_.w = (B.z >> 16) | (B.w & 0xffff0000u); \
    bf16x8 a_ = __builtin_bit_cast(bf16x8, u_); \
    acc0 = __builtin_amdgcn_mfma_f32_16x16x32_bf16(a_, __builtin_bit_cast(bf16x8, sB[1][0][KK][lane]), acc0, 0, 0, 0); \
    acc1 = __builtin_amdgcn_mfma_f32_16x16x32_bf16(a_, __builtin_bit_cast(bf16x8, sB[1][1][KK][lane]), acc1, 0, 0, 0); \
    acc2 = __builtin_amdgcn_mfma_f32_16x16x32_bf16(a_, __builtin_bit_cast(bf16x8, sB[1][2][KK][lane]), acc2, 0, 0, 0); \
    acc3 = __builtin_amdgcn_mfma_f32_16x16x32_bf16(a_, __builtin_bit_cast(bf16x8, sB[1][3][KK][lane]), acc3, 0, 0, 0); \
} while (0)

extern "C" __global__ void __launch_bounds__(256, 1)
lstm_fused(const float* __restrict__ x,
           const float* __restrict__ W_ih,
           const float* __restrict__ W_hh,
           const float* __restrict__ b_ih,
           const float* __restrict__ b_hh,
           float* __restrict__ out,
           unsigned int* __restrict__ hbuf,     // [2][64][512] tagged u32
           unsigned int* __restrict__ tickets)  // worker tickets
{
    // [matrix 0=W_ih,1=W_hh][gate ntile][kk][lane]: 16B = MFMA B-fragment
    __shared__ u32x4 sB[2][4][16][64];                       // 128 KB
    __shared__ __align__(16) unsigned int sHt[4][16][16];    // tagged publish
    __shared__ __align__(16) float        sHf[4][16][16];    // fp32 out
    __shared__ int sWid;

    const int tid = threadIdx.x;

    // ---- worker selection: only XCD 0, first NW tickets ----
    if (tid == 0) {
        unsigned int xcc;
        asm volatile("s_getreg_b32 %0, hwreg(HW_REG_XCC_ID)" : "=s"(xcc));
        int id = -1;
        if ((xcc & 0xfu) == 0u) {
            unsigned int tk = __hip_atomic_fetch_add(tickets, 1u,
                                 __ATOMIC_RELAXED, __HIP_MEMORY_SCOPE_AGENT);
            if (tk < NW) id = (int)tk;
        }
        sWid = id;
    }
    __syncthreads();
    const int wid = sWid;
    if (wid < 0) return;    // non-worker: exit immediately, free the CU

    const int w    = tid >> 6;    // wave 0..3 -> batch rows 16w..16w+15
    const int lane = tid & 63;
    const int l15  = lane & 15;
    const int quad = lane >> 4;
    const int hc0  = wid << 4;    // first owned h-column (16 per worker)

    // ---- one-time: stage W slices into LDS in B-fragment order ----
    for (int u = tid; u < 2 * 4 * 16 * 64; u += 256) {
        int m    = u >> 12;
        int nt   = (u >> 10) & 3;
        int kk   = (u >> 6) & 15;
        int ln   = u & 63;
        int grow = (nt << 9) + hc0 + (ln & 15);   // gate nt, col hc0+(ln&15)
        int k0   = (kk << 5) + ((ln >> 4) << 3);
        sB[m][nt][kk][ln] = cvt8((m ? W_hh : W_ih) + grow * 512 + k0);
    }

    // per-lane biases: lane col = hc0+l15, one per gate
    float bias0, bias1, bias2, bias3;
    {
        int c = hc0 + l15;
        bias0 = b_ih[c]        + b_hh[c];
        bias1 = b_ih[c + 512]  + b_hh[c + 512];
        bias2 = b_ih[c + 1024] + b_hh[c + 1024];
        bias3 = b_ih[c + 1536] + b_hh[c + 1536];
    }
    __syncthreads();   // sB ready; waves never re-sync after this

    float cst[4] = {0.f, 0.f, 0.f, 0.f};  // c-state rows quad*4+r, col hc0+l15
    const int arow = (w << 4) + l15;                  // A-fragment row (batch)
    const int aoff = arow * 512 + (quad << 3);        // x lane offset
    char* const hb = (char*)hbuf;
    // consumer read base: row-major [row][hcol], 2048 B/row; lane reads
    // h[arow][kk*32 + quad*8 + j] -> base + kk*128 (+16)
    char* const hrd_base = hb + arow * 2048 + (quad << 5);
    long long budget = 300000LL;          // deadlock safety valve

    for (int t = 0; t < T_STEPS; ++t) {
        f32x4 acc0 = {0.f,0.f,0.f,0.f}, acc1 = {0.f,0.f,0.f,0.f};
        f32x4 acc2 = {0.f,0.f,0.f,0.f}, acc3 = {0.f,0.f,0.f,0.f};

        // ---- x-projection: 16 kk x 4 gate-ntiles ----
        const float* xt = x + (size_t)t * (BATCH * 512) + aoff;
#pragma unroll
        for (int kk = 0; kk < 16; ++kk) {
            bf16x8 a = __builtin_bit_cast(bf16x8, cvt8(xt + kk * 32));
            acc0 = __builtin_amdgcn_mfma_f32_16x16x32_bf16(a, __builtin_bit_cast(bf16x8, sB[0][0][kk][lane]), acc0, 0, 0, 0);
            acc1 = __builtin_amdgcn_mfma_f32_16x16x32_bf16(a, __builtin_bit_cast(bf16x8, sB[0][1][kk][lane]), acc1, 0, 0, 0);
            acc2 = __builtin_amdgcn_mfma_f32_16x16x32_bf16(a, __builtin_bit_cast(bf16x8, sB[0][2][kk][lane]), acc2, 0, 0, 0);
            acc3 = __builtin_amdgcn_mfma_f32_16x16x32_bf16(a, __builtin_bit_cast(bf16x8, sB[0][3][kk][lane]), acc3, 0, 0, 0);
        }

        // ---- recurrent: retry-load tagged h via sc0 (XCD-local L2) ----
        if (t > 0) {
            const char* hrd = hrd_base + (((t - 1) & 1) << 17);
            const unsigned int tgt = (unsigned int)t;
            u32x4 h0,h1,h2,h3,h4,h5,h6,h7,h8,h9,h10,h11,h12,h13,h14,h15,
                  h16,h17,h18,h19,h20,h21,h22,h23,h24,h25,h26,h27,h28,h29,h30,h31;
            for (;;) {
                asm volatile(
                    "global_load_dwordx4 %[h0],  %[a], off offset:0 sc0\n\t"
                    "global_load_dwordx4 %[h1],  %[a], off offset:16 sc0\n\t"
                    "global_load_dwordx4 %[h2],  %[a], off offset:128 sc0\n\t"
                    "global_load_dwordx4 %[h3],  %[a], off offset:144 sc0\n\t"
                    "global_load_dwordx4 %[h4],  %[a], off offset:256 sc0\n\t"
                    "global_load_dwordx4 %[h5],  %[a], off offset:272 sc0\n\t"
                    "global_load_dwordx4 %[h6],  %[a], off offset:384 sc0\n\t"
                    "global_load_dwordx4 %[h7],  %[a], off offset:400 sc0\n\t"
                    "global_load_dwordx4 %[h8],  %[a], off offset:512 sc0\n\t"
                    "global_load_dwordx4 %[h9],  %[a], off offset:528 sc0\n\t"
                    "global_load_dwordx4 %[h10], %[a], off offset:640 sc0\n\t"
                    "global_load_dwordx4 %[h11], %[a], off offset:656 sc0\n\t"
                    "global_load_dwordx4 %[h12], %[a], off offset:768 sc0\n\t"
                    "global_load_dwordx4 %[h13], %[a], off offset:784 sc0\n\t"
                    "global_load_dwordx4 %[h14], %[a], off offset:896 sc0\n\t"
                    "global_load_dwordx4 %[h15], %[a], off offset:912 sc0\n\t"
                    "global_load_dwordx4 %[h16], %[a], off offset:1024 sc0\n\t"
                    "global_load_dwordx4 %[h17], %[a], off offset:1040 sc0\n\t"
                    "global_load_dwordx4 %[h18], %[a], off offset:1152 sc0\n\t"
                    "global_load_dwordx4 %[h19], %[a], off offset:1168 sc0\n\t"
                    "global_load_dwordx4 %[h20], %[a], off offset:1280 sc0\n\t"
                    "global_load_dwordx4 %[h21], %[a], off offset:1296 sc0\n\t"
                    "global_load_dwordx4 %[h22], %[a], off offset:1408 sc0\n\t"
                    "global_load_dwordx4 %[h23], %[a], off offset:1424 sc0\n\t"
                    "global_load_dwordx4 %[h24], %[a], off offset:1536 sc0\n\t"
                    "global_load_dwordx4 %[h25], %[a], off offset:1552 sc0\n\t"
                    "global_load_dwordx4 %[h26], %[a], off offset:1664 sc0\n\t"
                    "global_load_dwordx4 %[h27], %[a], off offset:1680 sc0\n\t"
                    "global_load_dwordx4 %[h28], %[a], off offset:1792 sc0\n\t"
                    "global_load_dwordx4 %[h29], %[a], off offset:1808 sc0\n\t"
                    "global_load_dwordx4 %[h30], %[a], off offset:1920 sc0\n\t"
                    "global_load_dwordx4 %[h31], %[a], off offset:1936 sc0\n\t"
                    "s_waitcnt vmcnt(0)"
                    : [h0]"=&v"(h0),  [h1]"=&v"(h1),  [h2]"=&v"(h2),  [h3]"=&v"(h3),
                      [h4]"=&v"(h4),  [h5]"=&v"(h5),  [h6]"=&v"(h6),  [h7]"=&v"(h7),
                      [h8]"=&v"(h8),  [h9]"=&v"(h9),  [h10]"=&v"(h10),[h11]"=&v"(h11),
                      [h12]"=&v"(h12),[h13]"=&v"(h13),[h14]"=&v"(h14),[h15]"=&v"(h15),
                      [h16]"=&v"(h16),[h17]"=&v"(h17),[h18]"=&v"(h18),[h19]"=&v"(h19),
                      [h20]"=&v"(h20),[h21]"=&v"(h21),[h22]"=&v"(h22),[h23]"=&v"(h23),
                      [h24]"=&v"(h24),[h25]"=&v"(h25),[h26]"=&v"(h26),[h27]"=&v"(h27),
                      [h28]"=&v"(h28),[h29]"=&v"(h29),[h30]"=&v"(h30),[h31]"=&v"(h31)
                    : [a]"v"(hrd)
                    : "memory");
                unsigned int m = 0;
                VAL4(h0);  VAL4(h1);  VAL4(h2);  VAL4(h3);
                VAL4(h4);  VAL4(h5);  VAL4(h6);  VAL4(h7);
                VAL4(h8);  VAL4(h9);  VAL4(h10); VAL4(h11);
                VAL4(h12); VAL4(h13); VAL4(h14); VAL4(h15);
                VAL4(h16); VAL4(h17); VAL4(h18); VAL4(h19);
                VAL4(h20); VAL4(h21); VAL4(h22); VAL4(h23);
                VAL4(h24); VAL4(h25); VAL4(h26); VAL4(h27);
                VAL4(h28); VAL4(h29); VAL4(h30); VAL4(h31);
                if (__all(m == 0)) break;
                if (--budget < 0) break;   // safety valve
            }
            FRAGMFMA(0,  h0,  h1);  FRAGMFMA(1,  h2,  h3);
            FRAGMFMA(2,  h4,  h5);  FRAGMFMA(3,  h6,  h7);
            FRAGMFMA(4,  h8,  h9);  FRAGMFMA(5,  h10, h11);
            FRAGMFMA(6,  h12, h13); FRAGMFMA(7,  h14, h15);
            FRAGMFMA(8,  h16, h17); FRAGMFMA(9,  h18, h19);
            FRAGMFMA(10, h20, h21); FRAGMFMA(11, h22, h23);
            FRAGMFMA(12, h24, h25); FRAGMFMA(13, h26, h27);
            FRAGMFMA(14, h28, h29); FRAGMFMA(15, h30, h31);
        }

        // ---- gates + state update (all 64 lanes; ntile == gate) ----
        // C-layout: col = l15 (hcol hc0+l15), row = quad*4 + r
        const unsigned int tagv = (unsigned int)(t + 1);
#pragma unroll
        for (int r = 0; r < 4; ++r) {
            float iv = sigmoidf_(acc0[r] + bias0);
            float fv = sigmoidf_(acc1[r] + bias1);
            float gv = tanhf_(acc2[r] + bias2);
            float ov = sigmoidf_(acc3[r] + bias3);
            cst[r] = fv * cst[r] + iv * gv;
            float hv = ov * tanhf_(cst[r]);
            sHt[w][(quad << 2) + r][l15] =
                ((unsigned int)f2bf(hv) << 16) | tagv;
            sHf[w][(quad << 2) + r][l15] = hv;
        }
        asm volatile("s_waitcnt lgkmcnt(0)" ::: "memory");

        // ---- publish: 64 lanes x 16B tagged sc0 stores (fire-and-forget) ----
        {
            int row16 = lane >> 2, seg = lane & 3;
            u32x4 v = *(const u32x4*)&sHt[w][row16][seg << 2];
            char* dst = hb + ((t & 1) << 17) + (((w << 4) + row16) * 2048)
                        + (hc0 << 2) + (seg << 4);
            asm volatile("global_store_dwordx4 %0, %1, off sc0"
                         :: "v"(dst), "v"(v) : "memory");
            // fp32 output store (off the critical chain)
            u32x4 vf = *(const u32x4*)&sHf[w][row16][seg << 2];
            float* op = out + (size_t)t * (BATCH * HID)
                        + (size_t)((w << 4) + row16) * HID + hc0 + (seg << 2);
            *(u32x4*)op = vf;
        }
    }
}

extern "C" void kernel_launch(void* const* d_in, const int* in_sizes, int n_in,
                              void* d_out, int out_size, void* d_ws, size_t ws_size,
                              hipStream_t stream) {
    const float* x    = (const float*)d_in[0];
    const float* W_ih = (const float*)d_in[1];
    const float* W_hh = (const float*)d_in[2];
    const float* b_ih = (const float*)d_in[3];
    const float* b_hh = (const float*)d_in[4];
    float* out = (float*)d_out;

    unsigned int* hbuf    = (unsigned int*)d_ws;
    unsigned int* tickets = (unsigned int*)((char*)d_ws + HBUF_BYTES);
    // zero tags (tag 0 never matches tgt>=1; clears harness 0xAA poison)
    // and the ticket counter
    (void)hipMemsetAsync(d_ws, 0, HBUF_BYTES + 64, stream);

    hipLaunchKernelGGL(lstm_fused, dim3(GRID), dim3(256), 0, stream,
                       x, W_ih, W_hh, b_ih, b_hh, out, hbuf, tickets);
}

// Round 7
// 4879.351 us; speedup vs baseline: 1.1004x; 1.1004x over previous
//
#include <hip/hip_runtime.h>

// LSTM: T=512, B=64, I=512, H=512. ROUND 14: INSTRUMENTATION round.
//  Refuted so far: sync mechanism (r9), x-proj load latency (r10), coherence
//  hop count (r11), clock/DPM (r12-counters: MfmaUtil 1.4% matches 2.4GHz
//  arithmetic exactly, would be ~9.5% at 400MHz), device-vs-XCD scope (r13:
//  L2-local comm was SLOWER with FETCH 14x lower).
//  ~17k of the 18.5k cycles/step are unplaced waiting. This round measures
//  WHERE: block0/wave0 accumulates s_memtime cycles spent in the retry-
//  rendezvous loop; after the t-loop, block0 tail-spins s_memrealtime for
//  (cycles/24) ticks == wait_us. READOUT: wait_total_us = dur_us - 3985.
//  Kernel logic is otherwise round-3 verbatim (tag-in-data, device scope).

#define T_STEPS 512
#define BATCH   64
#define HID     512
#define NB      64

typedef short bf16x8 __attribute__((ext_vector_type(8)));
typedef float f32x4  __attribute__((ext_vector_type(4)));

struct U16B { unsigned long long x, y; };

__device__ __forceinline__ unsigned short f2bf(float f) {
    unsigned int u = __builtin_bit_cast(unsigned int, f);
    u += 0x7FFFu + ((u >> 16) & 1u);
    return (unsigned short)(u >> 16);
}
__device__ __forceinline__ unsigned int pack2(float lo, float hi) {
    return (unsigned int)f2bf(lo) | ((unsigned int)f2bf(hi) << 16);
}
__device__ __forceinline__ uint4 cvt8(const float* __restrict__ p) {
    float4 f0 = *(const float4*)p;
    float4 f1 = *(const float4*)(p + 4);
    uint4 r;
    r.x = pack2(f0.x, f0.y);
    r.y = pack2(f0.z, f0.w);
    r.z = pack2(f1.x, f1.y);
    r.w = pack2(f1.z, f1.w);
    return r;
}
__device__ __forceinline__ void store_cg16(void* p, uint4 v) {
    unsigned long long* q = (unsigned long long*)p;
    U16B u = __builtin_bit_cast(U16B, v);
    __hip_atomic_store(q,     u.x, __ATOMIC_RELAXED, __HIP_MEMORY_SCOPE_AGENT);
    __hip_atomic_store(q + 1, u.y, __ATOMIC_RELAXED, __HIP_MEMORY_SCOPE_AGENT);
}
__device__ __forceinline__ float sigmoidf_(float x) {
    return 1.0f / (1.0f + __expf(-x));
}
__device__ __forceinline__ float tanhf_(float x) {
    x = fminf(fmaxf(x, -15.f), 15.f);
    float e = __expf(2.0f * x);
    return (e - 1.0f) / (e + 1.0f);
}

extern "C" __global__ void __launch_bounds__(256, 1)
lstm_fused(const float* __restrict__ x,
           const float* __restrict__ W_ih,
           const float* __restrict__ W_hh,
           const float* __restrict__ b_ih,
           const float* __restrict__ b_hh,
           float* __restrict__ out,
           unsigned int* __restrict__ hbuf)   // [2][NB][64 rows][8 cols] u32 tagged
{
    __shared__ uint4 sB[2][2][16][64];
    __shared__ __align__(16) unsigned int sHt[4][16][8];  // tagged words (publish)
    __shared__ __align__(16) float        sHf[4][16][8];  // fp32 (out stores)

    const int blk  = blockIdx.x;
    const int tid  = threadIdx.x;
    const int w    = tid >> 6;
    const int lane = tid & 63;
    const int l15  = lane & 15;
    const int quad = lane >> 4;
    const int hc0  = blk * 8;

    for (int u = tid; u < 2 * 16 * 64; u += 256) {
        int nt   = u >> 10;
        int kk   = (u >> 6) & 15;
        int ln   = u & 63;
        int c    = (ln & 15) + (nt << 4);
        int grow = ((c >> 3) << 9) + hc0 + (c & 7);
        int k0   = kk * 32 + ((ln >> 4) << 3);
        sB[0][nt][kk][ln] = cvt8(W_ih + grow * 512 + k0);
        sB[1][nt][kk][ln] = cvt8(W_hh + grow * 512 + k0);
    }

    float bias0, bias1;
    {
        int c0 = l15,      g0 = ((c0 >> 3) << 9) + hc0 + (c0 & 7);
        int c1 = l15 + 16, g1 = ((c1 >> 3) << 9) + hc0 + (c1 & 7);
        bias0 = b_ih[g0] + b_hh[g0];
        bias1 = b_ih[g1] + b_hh[g1];
    }
    __syncthreads();

    float cst[4] = {0.f, 0.f, 0.f, 0.f};
    const int aoff = (((w << 4) + l15) * 512) + (quad << 3);
    char* const hb_base  = (char*)hbuf;
    const int   hread_off = (quad << 11) + (((w << 4) + l15) << 5);
    long long budget = 2000000LL;

    // ---- instrumentation state (block 0, wave 0 only) ----
    const bool timed = (blk == 0) && (w == 0);
    unsigned long long wsum = 0;

    for (int t = 0; t < T_STEPS; ++t) {
        f32x4 acc0 = {0.f, 0.f, 0.f, 0.f};
        f32x4 acc1 = {0.f, 0.f, 0.f, 0.f};

        // ---- x-projection ----
        const float* xt = x + (size_t)t * (BATCH * 512) + aoff;
#pragma unroll
        for (int kk = 0; kk < 16; ++kk) {
            bf16x8 a  = __builtin_bit_cast(bf16x8, cvt8(xt + kk * 32));
            bf16x8 b0 = __builtin_bit_cast(bf16x8, sB[0][0][kk][lane]);
            bf16x8 b1 = __builtin_bit_cast(bf16x8, sB[0][1][kk][lane]);
            acc0 = __builtin_amdgcn_mfma_f32_16x16x32_bf16(a, b0, acc0, 0, 0, 0);
            acc1 = __builtin_amdgcn_mfma_f32_16x16x32_bf16(a, b1, acc1, 0, 0, 0);
        }

        // ---- recurrent part: retry-load tagged h until all tags == t ----
        if (t > 0) {
            unsigned long long c0 = 0;
            if (timed) c0 = __builtin_amdgcn_s_memtime();

            const char* hp = hb_base + (((t - 1) & 1) << 17) + hread_off;
            const unsigned int tgt = (unsigned int)t;
            unsigned long long hw[64];
            for (;;) {
#pragma unroll
                for (int kk = 0; kk < 16; ++kk) {
                    const unsigned long long* q =
                        (const unsigned long long*)(hp + (kk << 13));
#pragma unroll
                    for (int j = 0; j < 4; ++j)
                        hw[kk * 4 + j] = __hip_atomic_load(q + j, __ATOMIC_RELAXED,
                                                           __HIP_MEMORY_SCOPE_AGENT);
                }
                unsigned int m = 0;
#pragma unroll
                for (int i = 0; i < 64; ++i)
                    m |= ((unsigned int)hw[i] ^ tgt) & 0xffffu;
                if (__all(m == 0)) break;
                if (--budget < 0) break;
            }

            if (timed) wsum += __builtin_amdgcn_s_memtime() - c0;

#pragma unroll
            for (int kk = 0; kk < 16; ++kk) {
                unsigned int w0 = (unsigned int)(hw[4 * kk + 0]);
                unsigned int w1 = (unsigned int)(hw[4 * kk + 0] >> 32);
                unsigned int w2 = (unsigned int)(hw[4 * kk + 1]);
                unsigned int w3 = (unsigned int)(hw[4 * kk + 1] >> 32);
                unsigned int w4 = (unsigned int)(hw[4 * kk + 2]);
                unsigned int w5 = (unsigned int)(hw[4 * kk + 2] >> 32);
                unsigned int w6 = (unsigned int)(hw[4 * kk + 3]);
                unsigned int w7 = (unsigned int)(hw[4 * kk + 3] >> 32);
                uint4 u;
                u.x = (w0 >> 16) | (w1 & 0xffff0000u);
                u.y = (w2 >> 16) | (w3 & 0xffff0000u);
                u.z = (w4 >> 16) | (w5 & 0xffff0000u);
                u.w = (w6 >> 16) | (w7 & 0xffff0000u);
                bf16x8 a  = __builtin_bit_cast(bf16x8, u);
                bf16x8 b0 = __builtin_bit_cast(bf16x8, sB[1][0][kk][lane]);
                bf16x8 b1 = __builtin_bit_cast(bf16x8, sB[1][1][kk][lane]);
                acc0 = __builtin_amdgcn_mfma_f32_16x16x32_bf16(a, b0, acc0, 0, 0, 0);
                acc1 = __builtin_amdgcn_mfma_f32_16x16x32_bf16(a, b1, acc1, 0, 0, 0);
            }
        }

        // ---- gates + state update ----
        float gi[4], gf[4], gg[4], go[4];
#pragma unroll
        for (int r = 0; r < 4; ++r) {
            float a0 = acc0[r] + bias0;
            float a1 = acc1[r] + bias1;
            float p0 = __shfl_xor(a0, 8, 64);
            float p1 = __shfl_xor(a1, 8, 64);
            gi[r] = a0; gg[r] = a1; gf[r] = p0; go[r] = p1;
        }
        const unsigned int tagv = (unsigned int)(t + 1);
        if (l15 < 8) {
#pragma unroll
            for (int r = 0; r < 4; ++r) {
                float iv = sigmoidf_(gi[r]);
                float fv = sigmoidf_(gf[r]);
                float gv = tanhf_(gg[r]);
                float ov = sigmoidf_(go[r]);
                cst[r] = fv * cst[r] + iv * gv;
                float hv = ov * tanhf_(cst[r]);
                sHt[w][(quad << 2) + r][l15] =
                    ((unsigned int)f2bf(hv) << 16) | tagv;
                sHf[w][(quad << 2) + r][l15] = hv;
            }
        }
        asm volatile("s_waitcnt lgkmcnt(0)" ::: "memory");
        if (lane < 32) {
            int row  = lane >> 1;
            int half = lane & 1;
            uint4 v = *(const uint4*)&sHt[w][row][half << 2];
            char* dst = hb_base + ((t & 1) << 17) + (blk << 11)
                        + (((w << 4) + row) << 5) + (half << 4);
            store_cg16(dst, v);
        }

        if (lane < 32) {
            int row  = lane & 15;
            int half = lane >> 4;
            uint4 v = *(const uint4*)&sHf[w][row][half << 2];
            float* op = out + (size_t)t * (BATCH * HID)
                        + (size_t)((w << 4) + row) * HID + hc0 + (half << 2);
            *(uint4*)op = v;
        }
    }

    // ---- readout tail: extend block0's duration by wait_us ----
    // wsum cycles @2.4GHz -> us = wsum/2400 -> 100MHz ticks = wsum/24.
    if (blk == 0 && tid == 0) {
        unsigned long long ticks = wsum / 24ULL;
        if (ticks > 600000ULL) ticks = 600000ULL;   // cap +6ms
        unsigned long long r0 = __builtin_amdgcn_s_memrealtime();
        while (__builtin_amdgcn_s_memrealtime() - r0 < ticks)
            __builtin_amdgcn_s_sleep(8);
    }
}

extern "C" void kernel_launch(void* const* d_in, const int* in_sizes, int n_in,
                              void* d_out, int out_size, void* d_ws, size_t ws_size,
                              hipStream_t stream) {
    const float* x    = (const float*)d_in[0];
    const float* W_ih = (const float*)d_in[1];
    const float* W_hh = (const float*)d_in[2];
    const float* b_ih = (const float*)d_in[3];
    const float* b_hh = (const float*)d_in[4];
    float* out = (float*)d_out;

    unsigned int* hbuf = (unsigned int*)d_ws;
    (void)hipMemsetAsync(hbuf, 0, 2 * NB * 64 * 8 * sizeof(unsigned int), stream);

    hipLaunchKernelGGL(lstm_fused, dim3(NB), dim3(256), 0, stream,
                       x, W_ih, W_hh, b_ih, b_hh, out, hbuf);
}

// Round 8
// 4835.587 us; speedup vs baseline: 1.1104x; 1.0091x over previous
//
#include <hip/hip_runtime.h>

// LSTM: T=512, B=64, I=512, H=512. ROUND 15: vmcnt-hygiene reorder.
//  r14 instrumentation: rendezvous spin = 1.75us/step (23%). The other
//  ~6us/step is the recurrent->gates->stores->xproj stretch. Mechanism:
//  vmcnt retires IN ISSUE ORDER; in all prior rounds each step's x-loads
//  were issued AFTER the agent-scope publish stores, so consuming the
//  first x-load forced full retirement of all older stores (device-scope
//  ACK drain) -- every round paid this somewhere (r0: explicit vmcnt(0);
//  r1/r2: producer-side before flag; r3: implicitly inside xproj).
//  FIX: per step, issue next-step x-loads into registers BEFORE the
//  publish/out stores (sched_barrier-pinned), run xproj AFTER the stores
//  consuming those pre-issued loads -- their waits only count NEWER ops,
//  so stores stay in flight. Only the rendezvous vmcnt(0) still drains
//  stores, ~1us after issue (mostly retired by then).
//  xr[32] (xproj prefetch) and hw[64] (rendezvous) lifetimes are disjoint.

#define T_STEPS 512
#define BATCH   64
#define HID     512
#define NB      64

typedef short bf16x8 __attribute__((ext_vector_type(8)));
typedef float f32x4  __attribute__((ext_vector_type(4)));

__device__ __forceinline__ unsigned short f2bf(float f) {
    unsigned int u = __builtin_bit_cast(unsigned int, f);
    u += 0x7FFFu + ((u >> 16) & 1u);
    return (unsigned short)(u >> 16);
}
__device__ __forceinline__ unsigned int pack2(float lo, float hi) {
    return (unsigned int)f2bf(lo) | ((unsigned int)f2bf(hi) << 16);
}
__device__ __forceinline__ uint4 pack8(float4 f0, float4 f1) {
    uint4 r;
    r.x = pack2(f0.x, f0.y);
    r.y = pack2(f0.z, f0.w);
    r.z = pack2(f1.x, f1.y);
    r.w = pack2(f1.z, f1.w);
    return r;
}
__device__ __forceinline__ uint4 cvt8(const float* __restrict__ p) {
    float4 f0 = *(const float4*)p;
    float4 f1 = *(const float4*)(p + 4);
    return pack8(f0, f1);
}
__device__ __forceinline__ float sigmoidf_(float x) {
    return 1.0f / (1.0f + __expf(-x));
}
__device__ __forceinline__ float tanhf_(float x) {
    x = fminf(fmaxf(x, -15.f), 15.f);
    float e = __expf(2.0f * x);
    return (e - 1.0f) / (e + 1.0f);
}

extern "C" __global__ void __launch_bounds__(256, 1)
lstm_fused(const float* __restrict__ x,
           const float* __restrict__ W_ih,
           const float* __restrict__ W_hh,
           const float* __restrict__ b_ih,
           const float* __restrict__ b_hh,
           float* __restrict__ out,
           unsigned int* __restrict__ hbuf)   // [2][NB][64 rows][8 cols] u32 tagged
{
    __shared__ uint4 sB[2][2][16][64];
    __shared__ __align__(16) unsigned int sHt[4][16][8];  // tagged words (publish)
    __shared__ __align__(16) float        sHf[4][16][8];  // fp32 (out stores)

    const int blk  = blockIdx.x;
    const int tid  = threadIdx.x;
    const int w    = tid >> 6;
    const int lane = tid & 63;
    const int l15  = lane & 15;
    const int quad = lane >> 4;
    const int hc0  = blk * 8;

    for (int u = tid; u < 2 * 16 * 64; u += 256) {
        int nt   = u >> 10;
        int kk   = (u >> 6) & 15;
        int ln   = u & 63;
        int c    = (ln & 15) + (nt << 4);
        int grow = ((c >> 3) << 9) + hc0 + (c & 7);
        int k0   = kk * 32 + ((ln >> 4) << 3);
        sB[0][nt][kk][ln] = cvt8(W_ih + grow * 512 + k0);
        sB[1][nt][kk][ln] = cvt8(W_hh + grow * 512 + k0);
    }

    float bias0, bias1;
    {
        int c0 = l15,      g0 = ((c0 >> 3) << 9) + hc0 + (c0 & 7);
        int c1 = l15 + 16, g1 = ((c1 >> 3) << 9) + hc0 + (c1 & 7);
        bias0 = b_ih[g0] + b_hh[g0];
        bias1 = b_ih[g1] + b_hh[g1];
    }
    __syncthreads();

    float cst[4] = {0.f, 0.f, 0.f, 0.f};
    const int aoff = (((w << 4) + l15) * 512) + (quad << 3);
    char* const hb_base  = (char*)hbuf;
    const int   hread_off = (quad << 11) + (((w << 4) + l15) << 5);
    long long budget = 2000000LL;

    // ---- prologue: prefetch + x-projection for t=0 ----
    float4 xr[32];
    f32x4 accx0 = {0.f, 0.f, 0.f, 0.f};
    f32x4 accx1 = {0.f, 0.f, 0.f, 0.f};
    {
        const float* x0 = x + aoff;
#pragma unroll
        for (int kk = 0; kk < 16; ++kk) {
            xr[2 * kk]     = *(const float4*)(x0 + kk * 32);
            xr[2 * kk + 1] = *(const float4*)(x0 + kk * 32 + 4);
        }
#pragma unroll
        for (int kk = 0; kk < 16; ++kk) {
            bf16x8 a  = __builtin_bit_cast(bf16x8, pack8(xr[2 * kk], xr[2 * kk + 1]));
            bf16x8 b0 = __builtin_bit_cast(bf16x8, sB[0][0][kk][lane]);
            bf16x8 b1 = __builtin_bit_cast(bf16x8, sB[0][1][kk][lane]);
            accx0 = __builtin_amdgcn_mfma_f32_16x16x32_bf16(a, b0, accx0, 0, 0, 0);
            accx1 = __builtin_amdgcn_mfma_f32_16x16x32_bf16(a, b1, accx1, 0, 0, 0);
        }
    }

    for (int t = 0; t < T_STEPS; ++t) {
        // acc for this step starts from the pre-computed x-projection
        f32x4 acc0 = accx0;
        f32x4 acc1 = accx1;

        // ---- rendezvous: retry-load tagged h until all tags == t ----
        if (t > 0) {
            const char* hp = hb_base + (((t - 1) & 1) << 17) + hread_off;
            const unsigned int tgt = (unsigned int)t;
            unsigned long long hw[64];
            for (;;) {
#pragma unroll
                for (int kk = 0; kk < 16; ++kk) {
                    const unsigned long long* q =
                        (const unsigned long long*)(hp + (kk << 13));
#pragma unroll
                    for (int j = 0; j < 4; ++j)
                        hw[kk * 4 + j] = __hip_atomic_load(q + j, __ATOMIC_RELAXED,
                                                           __HIP_MEMORY_SCOPE_AGENT);
                }
                unsigned int m = 0;
#pragma unroll
                for (int i = 0; i < 64; ++i)
                    m |= ((unsigned int)hw[i] ^ tgt) & 0xffffu;
                if (__all(m == 0)) break;
                if (--budget < 0) break;
            }
#pragma unroll
            for (int kk = 0; kk < 16; ++kk) {
                unsigned int w0 = (unsigned int)(hw[4 * kk + 0]);
                unsigned int w1 = (unsigned int)(hw[4 * kk + 0] >> 32);
                unsigned int w2 = (unsigned int)(hw[4 * kk + 1]);
                unsigned int w3 = (unsigned int)(hw[4 * kk + 1] >> 32);
                unsigned int w4 = (unsigned int)(hw[4 * kk + 2]);
                unsigned int w5 = (unsigned int)(hw[4 * kk + 2] >> 32);
                unsigned int w6 = (unsigned int)(hw[4 * kk + 3]);
                unsigned int w7 = (unsigned int)(hw[4 * kk + 3] >> 32);
                uint4 u;
                u.x = (w0 >> 16) | (w1 & 0xffff0000u);
                u.y = (w2 >> 16) | (w3 & 0xffff0000u);
                u.z = (w4 >> 16) | (w5 & 0xffff0000u);
                u.w = (w6 >> 16) | (w7 & 0xffff0000u);
                bf16x8 a  = __builtin_bit_cast(bf16x8, u);
                bf16x8 b0 = __builtin_bit_cast(bf16x8, sB[1][0][kk][lane]);
                bf16x8 b1 = __builtin_bit_cast(bf16x8, sB[1][1][kk][lane]);
                acc0 = __builtin_amdgcn_mfma_f32_16x16x32_bf16(a, b0, acc0, 0, 0, 0);
                acc1 = __builtin_amdgcn_mfma_f32_16x16x32_bf16(a, b1, acc1, 0, 0, 0);
            }
        }

        // ---- gates + state update ----
        float gi[4], gf[4], gg[4], go[4];
#pragma unroll
        for (int r = 0; r < 4; ++r) {
            float a0 = acc0[r] + bias0;
            float a1 = acc1[r] + bias1;
            float p0 = __shfl_xor(a0, 8, 64);
            float p1 = __shfl_xor(a1, 8, 64);
            gi[r] = a0; gg[r] = a1; gf[r] = p0; go[r] = p1;
        }
        const unsigned int tagv = (unsigned int)(t + 1);
        if (l15 < 8) {
#pragma unroll
            for (int r = 0; r < 4; ++r) {
                float iv = sigmoidf_(gi[r]);
                float fv = sigmoidf_(gf[r]);
                float gv = tanhf_(gg[r]);
                float ov = sigmoidf_(go[r]);
                cst[r] = fv * cst[r] + iv * gv;
                float hv = ov * tanhf_(cst[r]);
                sHt[w][(quad << 2) + r][l15] =
                    ((unsigned int)f2bf(hv) << 16) | tagv;
                sHf[w][(quad << 2) + r][l15] = hv;
            }
        }
        asm volatile("s_waitcnt lgkmcnt(0)" ::: "memory");

        // ---- KEY REORDER: issue next-step x loads BEFORE any stores ----
        {
            const int tn = (t + 1 < T_STEPS) ? (t + 1) : t;
            const float* xn = x + (size_t)tn * (BATCH * 512) + aoff;
#pragma unroll
            for (int kk = 0; kk < 16; ++kk) {
                xr[2 * kk]     = *(const float4*)(xn + kk * 32);
                xr[2 * kk + 1] = *(const float4*)(xn + kk * 32 + 4);
            }
        }
        __builtin_amdgcn_sched_barrier(0);   // pin: loads above, stores below

        // ---- publish: 64 lanes x 8B tagged agent atomics (fire-and-forget) ----
        {
            int row  = lane >> 2;        // row within wave's M-tile
            int pair = lane & 3;         // which 8B of the 32B row-slice
            unsigned long long v =
                *(const unsigned long long*)&sHt[w][row][pair << 1];
            char* dst = hb_base + ((t & 1) << 17) + (blk << 11)
                        + (((w << 4) + row) << 5) + (pair << 3);
            __hip_atomic_store((unsigned long long*)dst, v,
                               __ATOMIC_RELAXED, __HIP_MEMORY_SCOPE_AGENT);
        }
        // ---- fp32 output stores (plain, L2-ack) ----
        if (lane < 32) {
            int row  = lane & 15;
            int half = lane >> 4;
            uint4 v = *(const uint4*)&sHf[w][row][half << 2];
            float* op = out + (size_t)t * (BATCH * HID)
                        + (size_t)((w << 4) + row) * HID + hc0 + (half << 2);
            *(uint4*)op = v;
        }
        __builtin_amdgcn_sched_barrier(0);   // pin: stores above, xproj below

        // ---- x-projection for t+1: consumes pre-store loads; its waits
        //      only count ops NEWER than each load -> stores stay in flight ----
        accx0 = (f32x4){0.f, 0.f, 0.f, 0.f};
        accx1 = (f32x4){0.f, 0.f, 0.f, 0.f};
#pragma unroll
        for (int kk = 0; kk < 16; ++kk) {
            bf16x8 a  = __builtin_bit_cast(bf16x8, pack8(xr[2 * kk], xr[2 * kk + 1]));
            bf16x8 b0 = __builtin_bit_cast(bf16x8, sB[0][0][kk][lane]);
            bf16x8 b1 = __builtin_bit_cast(bf16x8, sB[0][1][kk][lane]);
            accx0 = __builtin_amdgcn_mfma_f32_16x16x32_bf16(a, b0, accx0, 0, 0, 0);
            accx1 = __builtin_amdgcn_mfma_f32_16x16x32_bf16(a, b1, accx1, 0, 0, 0);
        }
    }
}

extern "C" void kernel_launch(void* const* d_in, const int* in_sizes, int n_in,
                              void* d_out, int out_size, void* d_ws, size_t ws_size,
                              hipStream_t stream) {
    const float* x    = (const float*)d_in[0];
    const float* W_ih = (const float*)d_in[1];
    const float* W_hh = (const float*)d_in[2];
    const float* b_ih = (const float*)d_in[3];
    const float* b_hh = (const float*)d_in[4];
    float* out = (float*)d_out;

    unsigned int* hbuf = (unsigned int*)d_ws;
    // zero tags (tag 0 never matches tgt>=1; clears harness 0xAA poison)
    (void)hipMemsetAsync(hbuf, 0, 2 * NB * 64 * 8 * sizeof(unsigned int), stream);

    hipLaunchKernelGGL(lstm_fused, dim3(NB), dim3(256), 0, stream,
                       x, W_ih, W_hh, b_ih, b_hh, out, hbuf);
}